// Round 2
// baseline (417.135 us; speedup 1.0000x reference)
//
#include <hip/hip_runtime.h>
#include <hip/hip_bf16.h>

typedef unsigned short u16;

using bf16x8 = __attribute__((ext_vector_type(8))) __bf16;
using f32x4  = __attribute__((ext_vector_type(4))) float;

#define NH    16
#define DKH   64
#define SEQ   2048
#define BAT   2
#define DMOD  1024
#define MROWS 4096

__device__ __forceinline__ u16 f2bf(float f) {
  union { float f; unsigned u; } v; v.f = f;
  unsigned r = v.u + 0x7fffu + ((v.u >> 16) & 1u);
  return (u16)(r >> 16);
}

// ---------------- weight transpose + fp32->bf16: Wt[n][k] = bf16(W[k][n]) ----------------
__global__ __launch_bounds__(256) void transpose_k(const float* __restrict__ W,
                                                   u16* __restrict__ Wt) {
  __shared__ u16 t[32][33];
  int bx = blockIdx.x * 32, by = blockIdx.y * 32;
  int x = threadIdx.x, y = threadIdx.y;
  #pragma unroll
  for (int i = 0; i < 32; i += 8)
    t[y + i][x] = f2bf(W[(size_t)(by + y + i) * DMOD + bx + x]);
  __syncthreads();
  #pragma unroll
  for (int i = 0; i < 32; i += 8)
    Wt[(size_t)(bx + y + i) * DMOD + by + x] = t[x][y + i];
}

// ---------------- GEMM: C[M=4096][N=1024] = A[4096][1024] * Bt[1024][1024]^T ----------------
// AFP32: A operand is fp32 in global (converted to bf16 while staging); else bf16.
// MODE 0: C row-major fp32 (final output)
// MODE 1: Q layout [b,h,s,dk] bf16, scaled by 1/8
// MODE 2: K layout [b,h,s,dk] bf16
// MODE 3: V^T layout [b,h,dk,s] bf16
#define LDA 40  // 32 cols + 8 pad

template<int AFP32, int MODE>
__global__ __launch_bounds__(256) void gemm_bt(const void* __restrict__ Av,
                                               const u16* __restrict__ Bt,
                                               void* __restrict__ Cv) {
  __shared__ __align__(16) u16 As[128 * LDA];
  __shared__ __align__(16) u16 Bs[128 * LDA];
  const int tid  = threadIdx.x;
  const int lane = tid & 63, wv = tid >> 6;
  const int wm   = wv >> 1, wn = wv & 1;
  const int lrow = lane & 15, quad = lane >> 4;
  const int tileM = blockIdx.x * 128, tileN = blockIdx.y * 128;

  const f32x4 fz = {0.f, 0.f, 0.f, 0.f};
  f32x4 acc[4][4];
  #pragma unroll
  for (int i = 0; i < 4; ++i)
    #pragma unroll
    for (int j = 0; j < 4; ++j) acc[i][j] = fz;

  for (int kt = 0; kt < DMOD; kt += 32) {
    // stage A-tile (128x32)
    if (AFP32) {
      const float* Af = (const float*)Av;
      #pragma unroll
      for (int i = 0; i < 4; ++i) {
        int c = tid + i * 256;          // 0..1023 float4-chunks
        int r = c >> 3, cg = (c & 7) * 4;
        float4 f = *(const float4*)(&Af[(size_t)(tileM + r) * DMOD + kt + cg]);
        ushort4 h = make_ushort4(f2bf(f.x), f2bf(f.y), f2bf(f.z), f2bf(f.w));
        *(ushort4*)(&As[r * LDA + cg]) = h;
      }
    } else {
      const u16* Ab = (const u16*)Av;
      #pragma unroll
      for (int i = 0; i < 2; ++i) {
        int c = tid + i * 256;          // 0..511 uint4-chunks
        int r = c >> 2, cg = (c & 3) * 8;
        *(uint4*)(&As[r * LDA + cg]) =
            *(const uint4*)(&Ab[(size_t)(tileM + r) * DMOD + kt + cg]);
      }
    }
    // stage Bt-tile (128x32), always bf16
    #pragma unroll
    for (int i = 0; i < 2; ++i) {
      int c = tid + i * 256;
      int r = c >> 2, cg = (c & 3) * 8;
      *(uint4*)(&Bs[r * LDA + cg]) =
          *(const uint4*)(&Bt[(size_t)(tileN + r) * DMOD + kt + cg]);
    }
    __syncthreads();
    bf16x8 af[4], bfr[4];
    #pragma unroll
    for (int mt = 0; mt < 4; ++mt)
      af[mt] = *(const bf16x8*)(&As[(wm * 64 + mt * 16 + lrow) * LDA + quad * 8]);
    #pragma unroll
    for (int nt = 0; nt < 4; ++nt)
      bfr[nt] = *(const bf16x8*)(&Bs[(wn * 64 + nt * 16 + lrow) * LDA + quad * 8]);
    #pragma unroll
    for (int mt = 0; mt < 4; ++mt)
      #pragma unroll
      for (int nt = 0; nt < 4; ++nt)
        acc[mt][nt] = __builtin_amdgcn_mfma_f32_16x16x32_bf16(af[mt], bfr[nt],
                                                              acc[mt][nt], 0, 0, 0);
    __syncthreads();
  }

  // epilogue
  #pragma unroll
  for (int mt = 0; mt < 4; ++mt) {
    #pragma unroll
    for (int nt = 0; nt < 4; ++nt) {
      #pragma unroll
      for (int r = 0; r < 4; ++r) {
        int gm = tileM + wm * 64 + mt * 16 + quad * 4 + r;
        int gn = tileN + wn * 64 + nt * 16 + lrow;
        float v = acc[mt][nt][r];
        if (MODE == 0) {
          ((float*)Cv)[(size_t)gm * DMOD + gn] = v;
        } else {
          u16* C = (u16*)Cv;
          int bb = gm >> 11, srow = gm & (SEQ - 1);
          int hh = gn >> 6,  dki  = gn & (DKH - 1);
          size_t bhi = (size_t)(bb * NH + hh);
          if (MODE == 1)
            C[(bhi * SEQ + srow) * DKH + dki] = f2bf(v * 0.125f);
          else if (MODE == 2)
            C[(bhi * SEQ + srow) * DKH + dki] = f2bf(v);
          else
            C[(bhi * DKH + dki) * SEQ + srow] = f2bf(v);
        }
      }
    }
  }
}

// ---------------- flash-style causal attention ----------------
// grid: (SEQ/128, BAT*NH); block 256 (4 waves); wave w owns q-rows [w*32, w*32+32)
#define QP 72    // Qs/Ks row stride (64 + 8 pad)
#define VP 136   // Vs/Ps row stride (128 + 8 pad)

__global__ __launch_bounds__(256) void attn_k(const u16* __restrict__ Q,
                                              const u16* __restrict__ Kb,
                                              const u16* __restrict__ Vt,
                                              u16* __restrict__ Og) {
  __shared__ __align__(16) u16 Qs[128 * QP];
  __shared__ __align__(16) u16 Ks[128 * QP];
  __shared__ __align__(16) u16 Vs[64 * VP];
  __shared__ __align__(16) u16 Ps[4][32 * VP];

  const int tid  = threadIdx.x;
  const int lane = tid & 63, w = tid >> 6;
  const int lrow = lane & 15, quad = lane >> 4;
  const int qt = blockIdx.x, bh = blockIdx.y;
  const int b = bh >> 4, h = bh & 15;

  const u16* Qbh = Q  + (size_t)bh * SEQ * DKH;
  const u16* Kbh = Kb + (size_t)bh * SEQ * DKH;
  const u16* Vbh = Vt + (size_t)bh * DKH * SEQ;

  for (int i = tid; i < 1024; i += 256) {
    int r = i >> 3, cg = (i & 7) * 8;
    *(uint4*)(&Qs[r * QP + cg]) =
        *(const uint4*)(&Qbh[(size_t)qt * 8192 + (size_t)i * 8]);
  }

  const f32x4 fz = {0.f, 0.f, 0.f, 0.f};
  f32x4 oacc[2][4];
  float mrow[2][4], lsum[2][4];
  #pragma unroll
  for (int mt = 0; mt < 2; ++mt) {
    #pragma unroll
    for (int n = 0; n < 4; ++n) oacc[mt][n] = fz;
    #pragma unroll
    for (int r = 0; r < 4; ++r) { mrow[mt][r] = -1e30f; lsum[mt][r] = 0.f; }
  }

  for (int j = 0; j <= qt; ++j) {
    for (int i = tid; i < 1024; i += 256) {
      int r = i >> 3, cg = (i & 7) * 8;
      *(uint4*)(&Ks[r * QP + cg]) =
          *(const uint4*)(&Kbh[(size_t)j * 8192 + (size_t)i * 8]);
    }
    for (int i = tid; i < 1024; i += 256) {
      int r = i >> 4, cg = (i & 15) * 8;
      *(uint4*)(&Vs[r * VP + cg]) =
          *(const uint4*)(&Vbh[(size_t)r * SEQ + j * 128 + cg]);
    }
    __syncthreads();

    f32x4 sacc[2][8];
    #pragma unroll
    for (int mt = 0; mt < 2; ++mt)
      #pragma unroll
      for (int nt = 0; nt < 8; ++nt) sacc[mt][nt] = fz;

    #pragma unroll
    for (int kk = 0; kk < 64; kk += 32) {
      bf16x8 aq[2], bk[8];
      #pragma unroll
      for (int mt = 0; mt < 2; ++mt)
        aq[mt] = *(const bf16x8*)(&Qs[(w * 32 + mt * 16 + lrow) * QP + kk + quad * 8]);
      #pragma unroll
      for (int nt = 0; nt < 8; ++nt)
        bk[nt] = *(const bf16x8*)(&Ks[(nt * 16 + lrow) * QP + kk + quad * 8]);
      #pragma unroll
      for (int mt = 0; mt < 2; ++mt)
        #pragma unroll
        for (int nt = 0; nt < 8; ++nt)
          sacc[mt][nt] = __builtin_amdgcn_mfma_f32_16x16x32_bf16(aq[mt], bk[nt],
                                                                 sacc[mt][nt], 0, 0, 0);
    }

    if (j == qt) {
      #pragma unroll
      for (int mt = 0; mt < 2; ++mt)
        #pragma unroll
        for (int nt = 0; nt < 8; ++nt)
          #pragma unroll
          for (int r = 0; r < 4; ++r) {
            int rloc = w * 32 + mt * 16 + quad * 4 + r;
            int cloc = nt * 16 + lrow;
            if (cloc > rloc) sacc[mt][nt][r] = -1e30f;
          }
    }

    float alpha[2][4];
    #pragma unroll
    for (int mt = 0; mt < 2; ++mt) {
      #pragma unroll
      for (int r = 0; r < 4; ++r) {
        float mx = -1e30f;
        #pragma unroll
        for (int nt = 0; nt < 8; ++nt) mx = fmaxf(mx, sacc[mt][nt][r]);
        #pragma unroll
        for (int off = 1; off < 16; off <<= 1) mx = fmaxf(mx, __shfl_xor(mx, off, 64));
        float mnew = fmaxf(mrow[mt][r], mx);
        float a = __expf(mrow[mt][r] - mnew);
        float s = 0.f;
        #pragma unroll
        for (int nt = 0; nt < 8; ++nt) {
          float p = __expf(sacc[mt][nt][r] - mnew);
          sacc[mt][nt][r] = p;
          s += p;
        }
        #pragma unroll
        for (int off = 1; off < 16; off <<= 1) s += __shfl_xor(s, off, 64);
        lsum[mt][r] = lsum[mt][r] * a + s;
        mrow[mt][r] = mnew;
        alpha[mt][r] = a;
      }
    }

    u16* Pw = Ps[w];
    #pragma unroll
    for (int mt = 0; mt < 2; ++mt)
      #pragma unroll
      for (int nt = 0; nt < 8; ++nt)
        #pragma unroll
        for (int r = 0; r < 4; ++r)
          Pw[(mt * 16 + quad * 4 + r) * VP + nt * 16 + lrow] = f2bf(sacc[mt][nt][r]);
    #pragma unroll
    for (int mt = 0; mt < 2; ++mt)
      #pragma unroll
      for (int n = 0; n < 4; ++n)
        #pragma unroll
        for (int r = 0; r < 4; ++r) oacc[mt][n][r] *= alpha[mt][r];

    __syncthreads();

    #pragma unroll
    for (int kk = 0; kk < 128; kk += 32) {
      bf16x8 ap[2], bv[4];
      #pragma unroll
      for (int mt = 0; mt < 2; ++mt)
        ap[mt] = *(const bf16x8*)(&Pw[(mt * 16 + lrow) * VP + kk + quad * 8]);
      #pragma unroll
      for (int n = 0; n < 4; ++n)
        bv[n] = *(const bf16x8*)(&Vs[(n * 16 + lrow) * VP + kk + quad * 8]);
      #pragma unroll
      for (int mt = 0; mt < 2; ++mt)
        #pragma unroll
        for (int n = 0; n < 4; ++n)
          oacc[mt][n] = __builtin_amdgcn_mfma_f32_16x16x32_bf16(ap[mt], bv[n],
                                                                oacc[mt][n], 0, 0, 0);
    }
    __syncthreads();
  }

  #pragma unroll
  for (int mt = 0; mt < 2; ++mt)
    #pragma unroll
    for (int n = 0; n < 4; ++n)
      #pragma unroll
      for (int r = 0; r < 4; ++r) {
        int qrow = qt * 128 + w * 32 + mt * 16 + quad * 4 + r;
        int col  = n * 16 + lrow;
        float v  = oacc[mt][n][r] / lsum[mt][r];
        Og[((size_t)(b * SEQ + qrow)) * DMOD + h * DKH + col] = f2bf(v);
      }
}

// ---------------- launch ----------------
extern "C" void kernel_launch(void* const* d_in, const int* in_sizes, int n_in,
                              void* d_out, int out_size, void* d_ws, size_t ws_size,
                              hipStream_t stream) {
  const float* x  = (const float*)d_in[0];
  const float* Wq = (const float*)d_in[1];
  const float* Wk = (const float*)d_in[2];
  const float* Wv = (const float*)d_in[3];
  const float* Wo = (const float*)d_in[4];

  u16* ws  = (u16*)d_ws;
  const size_t WSZ = (size_t)DMOD * DMOD;           // 1M bf16 per weight
  const size_t TSZ = (size_t)BAT * NH * SEQ * DKH;  // 4M bf16 per tensor
  u16* Wtq = ws;
  u16* Wtk = Wtq + WSZ;
  u16* Wtv = Wtk + WSZ;
  u16* Wto = Wtv + WSZ;
  u16* Qb  = Wto + WSZ;
  u16* Kb  = Qb + TSZ;
  u16* Vtb = Kb + TSZ;
  u16* Ob  = Vtb + TSZ;

  dim3 tb(32, 8);
  transpose_k<<<dim3(32, 32), tb, 0, stream>>>(Wq, Wtq);
  transpose_k<<<dim3(32, 32), tb, 0, stream>>>(Wk, Wtk);
  transpose_k<<<dim3(32, 32), tb, 0, stream>>>(Wv, Wtv);
  transpose_k<<<dim3(32, 32), tb, 0, stream>>>(Wo, Wto);

  gemm_bt<1, 1><<<dim3(32, 8), 256, 0, stream>>>((const void*)x, Wtq, (void*)Qb);
  gemm_bt<1, 2><<<dim3(32, 8), 256, 0, stream>>>((const void*)x, Wtk, (void*)Kb);
  gemm_bt<1, 3><<<dim3(32, 8), 256, 0, stream>>>((const void*)x, Wtv, (void*)Vtb);

  attn_k<<<dim3(SEQ / 128, BAT * NH), 256, 0, stream>>>(Qb, Kb, Vtb, Ob);

  gemm_bt<0, 0><<<dim3(32, 8), 256, 0, stream>>>((const void*)Ob, Wto, d_out);
}

// Round 3
// 249.190 us; speedup vs baseline: 1.6740x; 1.6740x over previous
//
#include <hip/hip_runtime.h>

typedef unsigned short u16;
typedef unsigned int   u32;

using bf16x8 = __attribute__((ext_vector_type(8))) __bf16;
using f32x4  = __attribute__((ext_vector_type(4))) float;
using s16x4  = __attribute__((ext_vector_type(4))) short;

#define NH    16
#define DKH   64
#define SEQ   2048
#define BAT   2
#define DMOD  1024

__device__ __forceinline__ u16 f2bf(float f) {
  union { float f; u32 u; } v; v.f = f;
  u32 r = v.u + 0x7fffu + ((v.u >> 16) & 1u);
  return (u16)(r >> 16);
}

// two fp32 -> packed bf16 pair (RNE), low = a, high = b
__device__ __forceinline__ u32 pack2bf(float a, float b) {
  union { float f; u32 u; } x, y; x.f = a; y.f = b;
  u32 ua = x.u + 0x7fffu + ((x.u >> 16) & 1u);
  u32 ub = y.u + 0x7fffu + ((y.u >> 16) & 1u);
  return __builtin_amdgcn_perm(ub, ua, 0x07060302u);
}

// async global->LDS, 16B per lane; LDS dest = wave-uniform base + lane*16
__device__ __forceinline__ void gll16(const u16* g, u16* l) {
  __builtin_amdgcn_global_load_lds((__attribute__((address_space(1))) void*)(u16*)g,
                                   (__attribute__((address_space(3))) void*)l,
                                   16, 0, 0);
}

#if __has_builtin(__builtin_amdgcn_mfma_f32_16x16x16bf16_1k)
__device__ __forceinline__ f32x4 mfma16(s16x4 a, s16x4 b, f32x4 c) {
  return __builtin_amdgcn_mfma_f32_16x16x16bf16_1k(a, b, c, 0, 0, 0);
}
#else
__device__ __forceinline__ f32x4 mfma16(s16x4 a, s16x4 b, f32x4 c) {
  f32x4 d;
  asm volatile("v_mfma_f32_16x16x16_bf16 %0, %1, %2, %3\n\ts_nop 7\n\ts_nop 7"
               : "=v"(d) : "v"(a), "v"(b), "v"(c));
  return d;
}
#endif

// ---------------- fused 4x weight transpose + fp32->bf16 ----------------
__global__ __launch_bounds__(256) void transpose_all(const float* __restrict__ Wq,
                                                     const float* __restrict__ Wk,
                                                     const float* __restrict__ Wv,
                                                     const float* __restrict__ Wo,
                                                     u16* __restrict__ Wt) {
  __shared__ u16 t[32][33];
  const float* W = blockIdx.z == 0 ? Wq : blockIdx.z == 1 ? Wk : blockIdx.z == 2 ? Wv : Wo;
  u16* o = Wt + (size_t)blockIdx.z * DMOD * DMOD;
  int bx = blockIdx.x * 32, by = blockIdx.y * 32;
  int x = threadIdx.x, y = threadIdx.y;
  #pragma unroll
  for (int i = 0; i < 32; i += 8)
    t[y + i][x] = f2bf(W[(size_t)(by + y + i) * DMOD + bx + x]);
  __syncthreads();
  #pragma unroll
  for (int i = 0; i < 32; i += 8)
    o[(size_t)(bx + y + i) * DMOD + by + x] = t[x][y + i];
}

// ---------------- x fp32 -> bf16 ----------------
__global__ __launch_bounds__(256) void convert_x(const float* __restrict__ x,
                                                 u16* __restrict__ xb) {
  size_t i = ((size_t)blockIdx.x * 256 + threadIdx.x) * 8;
  float4 f0 = *(const float4*)(x + i);
  float4 f1 = *(const float4*)(x + i + 4);
  uint4 o;
  o.x = pack2bf(f0.x, f0.y); o.y = pack2bf(f0.z, f0.w);
  o.z = pack2bf(f1.x, f1.y); o.w = pack2bf(f1.z, f1.w);
  *(uint4*)(xb + i) = o;
}

// ---------------- GEMM (m97 structure): C = A[M x 1024] * Bt[N x 1024]^T ----------------
// MODE 0: write fp32 row-major to Co
// MODE 1: fused QKV epilogue (N = 3072), writes Qo ([b,h,s,dk] *0.125), Ko ([b,h,s,dk]), Vo ([b,h,dk,s])
template<int MODE>
__global__ __launch_bounds__(256) void gemm2(const u16* __restrict__ A,
                                             const u16* __restrict__ Bt,
                                             float* __restrict__ Co,
                                             u16* __restrict__ Qo,
                                             u16* __restrict__ Ko,
                                             u16* __restrict__ Vo) {
  __shared__ __align__(16) u16 As[128 * 32];   // unpadded: required by global_load_lds
  __shared__ __align__(16) u16 Bs[128 * 32];
  const int tid  = threadIdx.x;
  const int lane = tid & 63, wv = tid >> 6;
  const int wm   = wv >> 1, wn = wv & 1;
  const int lrow = lane & 15, quad = lane >> 4;
  const int tileM = blockIdx.x * 128, tileN = blockIdx.y * 128;
  const int srow = lane >> 2, scol = (lane & 3) * 8;   // staging: 16 rows x 64B per wave-call

  const f32x4 fz = {0.f, 0.f, 0.f, 0.f};
  f32x4 acc[4][4];
  #pragma unroll
  for (int i = 0; i < 4; ++i)
    #pragma unroll
    for (int j = 0; j < 4; ++j) acc[i][j] = fz;

  for (int kt = 0; kt < DMOD; kt += 32) {
    #pragma unroll
    for (int i = 0; i < 2; ++i) {
      int rr = wv * 32 + i * 16 + srow;
      gll16(&A [(size_t)(tileM + rr) * DMOD + kt + scol], &As[(wv * 32 + i * 16) * 32]);
      gll16(&Bt[(size_t)(tileN + rr) * DMOD + kt + scol], &Bs[(wv * 32 + i * 16) * 32]);
    }
    __syncthreads();
    bf16x8 af[4], bfr[4];
    #pragma unroll
    for (int mt = 0; mt < 4; ++mt)
      af[mt] = *(const bf16x8*)(&As[(wm * 64 + mt * 16 + lrow) * 32 + quad * 8]);
    #pragma unroll
    for (int nt = 0; nt < 4; ++nt)
      bfr[nt] = *(const bf16x8*)(&Bs[(wn * 64 + nt * 16 + lrow) * 32 + quad * 8]);
    #pragma unroll
    for (int mt = 0; mt < 4; ++mt)
      #pragma unroll
      for (int nt = 0; nt < 4; ++nt)
        acc[mt][nt] = __builtin_amdgcn_mfma_f32_16x16x32_bf16(af[mt], bfr[nt],
                                                              acc[mt][nt], 0, 0, 0);
    __syncthreads();
  }

  #pragma unroll
  for (int mt = 0; mt < 4; ++mt) {
    #pragma unroll
    for (int nt = 0; nt < 4; ++nt) {
      #pragma unroll
      for (int r = 0; r < 4; ++r) {
        int gm = tileM + wm * 64 + mt * 16 + quad * 4 + r;
        int gn = tileN + wn * 64 + nt * 16 + lrow;
        float v = acc[mt][nt][r];
        if (MODE == 0) {
          Co[(size_t)gm * DMOD + gn] = v;
        } else {
          int which = gn >> 10, col = gn & 1023;
          int bb = gm >> 11, srw = gm & (SEQ - 1);
          int hh = col >> 6, dki = col & (DKH - 1);
          size_t bhi = (size_t)(bb * NH + hh);
          if (which == 0)
            Qo[(bhi * SEQ + srw) * DKH + dki] = f2bf(v * 0.125f);
          else if (which == 1)
            Ko[(bhi * SEQ + srw) * DKH + dki] = f2bf(v);
          else
            Vo[(bhi * DKH + dki) * SEQ + srw] = f2bf(v);
        }
      }
    }
  }
}

// ---------------- causal flash attention, S^T formulation ----------------
// grid (16, BAT*NH); block 256 = 4 waves. Block p handles q-tiles {p, 31-p} (64 rows each,
// balanced). Wave w owns 16 q-columns. S^T = K.Q^T so each lane holds one q-column:
// softmax = in-lane + 2 shfls; P^T feeds PV (O^T = V^T.P^T) straight from registers
// via mfma_f32_16x16x16_bf16 (B-frag k=quad*4+j == C-layout row) -- no LDS round-trip.
#define QP 72    // 64 + 8 pad
#define VP 136   // 128 + 8 pad

__global__ __launch_bounds__(256) void attn_k(const u16* __restrict__ Q,
                                              const u16* __restrict__ Kg,
                                              const u16* __restrict__ Vt,
                                              u16* __restrict__ Og) {
  __shared__ __align__(16) u16 Qs[64 * QP];
  __shared__ __align__(16) u16 Ks[128 * QP];
  __shared__ __align__(16) u16 Vs[64 * VP];

  const int tid  = threadIdx.x;
  const int lane = tid & 63, w = tid >> 6;
  const int lrow = lane & 15, quad = lane >> 4;
  const int pair = blockIdx.x, bh = blockIdx.y;
  const int b = bh >> 4, h = bh & 15;

  const u16* Qbh = Q  + (size_t)bh * SEQ * DKH;
  const u16* Kbh = Kg + (size_t)bh * SEQ * DKH;
  const u16* Vbh = Vt + (size_t)bh * DKH * SEQ;

  for (int half = 0; half < 2; ++half) {
    const int qt = half ? (31 - pair) : pair;
    __syncthreads();
    for (int i = tid; i < 512; i += 256) {
      int r = i >> 3, cg = (i & 7) * 8;
      *(uint4*)(&Qs[r * QP + cg]) = *(const uint4*)(&Qbh[(size_t)(qt * 64 + r) * DKH + cg]);
    }

    const int qglob = qt * 64 + w * 16 + lrow;   // this lane's q column
    const int qmaxw = qt * 64 + w * 16 + 15;     // wave-uniform
    const f32x4 fz = {0.f, 0.f, 0.f, 0.f};
    f32x4 oacc[4];
    #pragma unroll
    for (int d = 0; d < 4; ++d) oacc[d] = fz;
    float mrow = -1e30f, lsum = 0.f;

    const int jmax = qt >> 1;
    for (int j = 0; j <= jmax; ++j) {
      for (int i = tid; i < 1024; i += 256) {
        int r = i >> 3, cg = (i & 7) * 8;
        *(uint4*)(&Ks[r * QP + cg]) =
            *(const uint4*)(&Kbh[(size_t)(j * 128 + r) * DKH + cg]);
      }
      for (int i = tid; i < 1024; i += 256) {
        int r = i >> 4, cg = (i & 15) * 8;
        *(uint4*)(&Vs[r * VP + cg]) =
            *(const uint4*)(&Vbh[(size_t)r * SEQ + j * 128 + cg]);
      }
      __syncthreads();

      // skip k-blocks fully above the diagonal (wave-uniform)
      const int mlim = (j == jmax) ? (((qmaxw - j * 128) >> 4) + 1) : 8;

      f32x4 sacc[8];
      #pragma unroll
      for (int m = 0; m < 8; ++m) sacc[m] = fz;

      #pragma unroll
      for (int kk = 0; kk < 2; ++kk) {
        bf16x8 bq = *(const bf16x8*)(&Qs[(w * 16 + lrow) * QP + kk * 32 + quad * 8]);
        #pragma unroll
        for (int m = 0; m < 8; ++m)
          if (m < mlim) {
            bf16x8 ak = *(const bf16x8*)(&Ks[(m * 16 + lrow) * QP + kk * 32 + quad * 8]);
            sacc[m] = __builtin_amdgcn_mfma_f32_16x16x32_bf16(ak, bq, sacc[m], 0, 0, 0);
          }
      }

      if (j == jmax) {   // triangle mask on diagonal tile
        #pragma unroll
        for (int m = 0; m < 8; ++m)
          if (m < mlim)
            #pragma unroll
            for (int r = 0; r < 4; ++r) {
              int kg = j * 128 + m * 16 + quad * 4 + r;
              if (kg > qglob) sacc[m][r] = -1e30f;
            }
      }

      // online softmax: per-lane over 4*mlim values, then combine 4 quads
      float mx = -1e30f;
      #pragma unroll
      for (int m = 0; m < 8; ++m)
        if (m < mlim)
          #pragma unroll
          for (int r = 0; r < 4; ++r) mx = fmaxf(mx, sacc[m][r]);
      mx = fmaxf(mx, __shfl_xor(mx, 16, 64));
      mx = fmaxf(mx, __shfl_xor(mx, 32, 64));
      float mnew = fmaxf(mrow, mx);
      float a = __expf(mrow - mnew);
      float s = 0.f;
      #pragma unroll
      for (int m = 0; m < 8; ++m)
        if (m < mlim)
          #pragma unroll
          for (int r = 0; r < 4; ++r) {
            float p = __expf(sacc[m][r] - mnew);
            sacc[m][r] = p;
            s += p;
          }
      s += __shfl_xor(s, 16, 64);
      s += __shfl_xor(s, 32, 64);
      lsum = lsum * a + s;
      mrow = mnew;
      #pragma unroll
      for (int d = 0; d < 4; ++d) oacc[d] *= a;

      // PV: O^T += V^T . P^T, P straight from registers
      #pragma unroll
      for (int m = 0; m < 8; ++m)
        if (m < mlim) {
          union { u32 u[2]; s16x4 v; } pk;
          pk.u[0] = pack2bf(sacc[m][0], sacc[m][1]);
          pk.u[1] = pack2bf(sacc[m][2], sacc[m][3]);
          #pragma unroll
          for (int d = 0; d < 4; ++d) {
            s16x4 av = *(const s16x4*)(&Vs[(d * 16 + lrow) * VP + m * 16 + quad * 4]);
            oacc[d] = mfma16(av, pk.v, oacc[d]);
          }
        }
      __syncthreads();
    }

    // epilogue: O = O^T^T / l, merge heads
    float inv = 1.f / lsum;
    #pragma unroll
    for (int d = 0; d < 4; ++d)
      #pragma unroll
      for (int r = 0; r < 4; ++r) {
        int dg = d * 16 + quad * 4 + r;
        Og[((size_t)(b * SEQ + qglob)) * DMOD + h * DKH + dg] = f2bf(oacc[d][r] * inv);
      }
  }
}

// ---------------- launch ----------------
extern "C" void kernel_launch(void* const* d_in, const int* in_sizes, int n_in,
                              void* d_out, int out_size, void* d_ws, size_t ws_size,
                              hipStream_t stream) {
  const float* x  = (const float*)d_in[0];
  const float* Wq = (const float*)d_in[1];
  const float* Wk = (const float*)d_in[2];
  const float* Wv = (const float*)d_in[3];
  const float* Wo = (const float*)d_in[4];

  u16* ws = (u16*)d_ws;
  const size_t WSZ = (size_t)DMOD * DMOD;
  const size_t TSZ = (size_t)BAT * NH * SEQ * DKH;
  u16* Wt  = ws;                 // [Wtq | Wtk | Wtv | Wto], 4 MB each... 4 x 1M elems
  u16* Wto = Wt + 3 * WSZ;
  u16* xb  = Wt + 4 * WSZ;       // x as bf16; later reused as Ob (attn output)
  u16* Qb  = xb + TSZ;
  u16* Kb  = Qb + TSZ;
  u16* Vtb = Kb + TSZ;
  u16* Ob  = xb;                 // alias: xb dead after QKV GEMM

  transpose_all<<<dim3(32, 32, 4), dim3(32, 8), 0, stream>>>(Wq, Wk, Wv, Wo, Wt);
  convert_x<<<dim3(2048), 256, 0, stream>>>(x, xb);

  gemm2<1><<<dim3(32, 24), 256, 0, stream>>>(xb, Wt, nullptr, Qb, Kb, Vtb);

  attn_k<<<dim3(16, BAT * NH), 256, 0, stream>>>(Qb, Kb, Vtb, Ob);

  gemm2<0><<<dim3(32, 8), 256, 0, stream>>>(Ob, Wto, (float*)d_out, nullptr, nullptr, nullptr);
}

// Round 4
// 224.089 us; speedup vs baseline: 1.8615x; 1.1120x over previous
//
#include <hip/hip_runtime.h>

typedef unsigned short u16;
typedef unsigned int   u32;

using bf16x8 = __attribute__((ext_vector_type(8))) __bf16;
using f32x4  = __attribute__((ext_vector_type(4))) float;
using s16x4  = __attribute__((ext_vector_type(4))) short;

#define NH    16
#define DKH   64
#define SEQ   2048
#define BAT   2
#define DMOD  1024

__device__ __forceinline__ u16 f2bf(float f) {
  union { float f; u32 u; } v; v.f = f;
  u32 r = v.u + 0x7fffu + ((v.u >> 16) & 1u);
  return (u16)(r >> 16);
}

__device__ __forceinline__ u32 pack2bf(float a, float b) {
  union { float f; u32 u; } x, y; x.f = a; y.f = b;
  u32 ua = x.u + 0x7fffu + ((x.u >> 16) & 1u);
  u32 ub = y.u + 0x7fffu + ((y.u >> 16) & 1u);
  return __builtin_amdgcn_perm(ub, ua, 0x07060302u);
}

// async global->LDS, 16B/lane; dest must be wave-uniform base (+lane*16 by HW)
__device__ __forceinline__ void gll16(const u16* g, u16* l) {
  __builtin_amdgcn_global_load_lds((__attribute__((address_space(1))) void*)(u16*)g,
                                   (__attribute__((address_space(3))) void*)l,
                                   16, 0, 0);
}

#if __has_builtin(__builtin_amdgcn_mfma_f32_16x16x16bf16_1k)
__device__ __forceinline__ f32x4 mfma16(s16x4 a, s16x4 b, f32x4 c) {
  return __builtin_amdgcn_mfma_f32_16x16x16bf16_1k(a, b, c, 0, 0, 0);
}
#else
__device__ __forceinline__ f32x4 mfma16(s16x4 a, s16x4 b, f32x4 c) {
  f32x4 d;
  asm volatile("v_mfma_f32_16x16x16_bf16 %0, %1, %2, %3\n\ts_nop 7\n\ts_nop 7"
               : "=v"(d) : "v"(a), "v"(b), "v"(c));
  return d;
}
#endif

// ---------------- fused 4x weight transpose + fp32->bf16 ----------------
__global__ __launch_bounds__(256) void transpose_all(const float* __restrict__ Wq,
                                                     const float* __restrict__ Wk,
                                                     const float* __restrict__ Wv,
                                                     const float* __restrict__ Wo,
                                                     u16* __restrict__ Wt) {
  __shared__ u16 t[32][33];
  const float* W = blockIdx.z == 0 ? Wq : blockIdx.z == 1 ? Wk : blockIdx.z == 2 ? Wv : Wo;
  u16* o = Wt + (size_t)blockIdx.z * DMOD * DMOD;
  int bx = blockIdx.x * 32, by = blockIdx.y * 32;
  int x = threadIdx.x, y = threadIdx.y;
  #pragma unroll
  for (int i = 0; i < 32; i += 8)
    t[y + i][x] = f2bf(W[(size_t)(by + y + i) * DMOD + bx + x]);
  __syncthreads();
  #pragma unroll
  for (int i = 0; i < 32; i += 8)
    o[(size_t)(bx + y + i) * DMOD + by + x] = t[x][y + i];
}

// ---------------- x fp32 -> bf16 ----------------
__global__ __launch_bounds__(256) void convert_x(const float* __restrict__ x,
                                                 u16* __restrict__ xb) {
  size_t i = ((size_t)blockIdx.x * 256 + threadIdx.x) * 8;
  float4 f0 = *(const float4*)(x + i);
  float4 f1 = *(const float4*)(x + i + 4);
  uint4 o;
  o.x = pack2bf(f0.x, f0.y); o.y = pack2bf(f0.z, f0.w);
  o.z = pack2bf(f1.x, f1.y); o.w = pack2bf(f1.z, f1.w);
  *(uint4*)(xb + i) = o;
}

// ---------------- V transpose: Vo[b,h,s,dk] -> Vt[b,h,dk,s] ----------------
__global__ __launch_bounds__(256) void vtrans(const u16* __restrict__ Vo,
                                              u16* __restrict__ Vt) {
  __shared__ u16 t[32][33];
  const u16* in = Vo + (size_t)blockIdx.z * SEQ * DKH;
  u16* out      = Vt + (size_t)blockIdx.z * DKH * SEQ;
  int bx = blockIdx.x * 32, by = blockIdx.y * 32;   // bx: s, by: dk
  int x = threadIdx.x, y = threadIdx.y;
  #pragma unroll
  for (int i = 0; i < 32; i += 8)
    t[y + i][x] = in[(size_t)(bx + y + i) * DKH + by + x];
  __syncthreads();
  #pragma unroll
  for (int i = 0; i < 32; i += 8)
    out[(size_t)(by + y + i) * SEQ + bx + x] = t[x][y + i];
}

// ---------------- QKV GEMM: [4096 x 1024] * [3072 x 1024]^T, fused epilogue ----------------
// writes Qo ([b,h,s,dk] *0.125), Ko ([b,h,s,dk]), Vo ([b,h,s,dk] -- coalesced)
__global__ __launch_bounds__(256) void gemm_qkv(const u16* __restrict__ A,
                                                const u16* __restrict__ Bt,
                                                u16* __restrict__ Qo,
                                                u16* __restrict__ Ko,
                                                u16* __restrict__ Vo) {
  __shared__ __align__(16) u16 As[128 * 32];
  __shared__ __align__(16) u16 Bs[128 * 32];
  const int tid  = threadIdx.x;
  const int lane = tid & 63, wv = tid >> 6;
  const int wm   = wv >> 1, wn = wv & 1;
  const int lrow = lane & 15, quad = lane >> 4;
  const int tileM = blockIdx.x * 128, tileN = blockIdx.y * 128;
  const int srow = lane >> 2, scol = (lane & 3) * 8;

  const f32x4 fz = {0.f, 0.f, 0.f, 0.f};
  f32x4 acc[4][4];
  #pragma unroll
  for (int i = 0; i < 4; ++i)
    #pragma unroll
    for (int j = 0; j < 4; ++j) acc[i][j] = fz;

  for (int kt = 0; kt < DMOD; kt += 32) {
    #pragma unroll
    for (int i = 0; i < 2; ++i) {
      int rr = wv * 32 + i * 16 + srow;
      gll16(&A [(size_t)(tileM + rr) * DMOD + kt + scol], &As[(wv * 32 + i * 16) * 32]);
      gll16(&Bt[(size_t)(tileN + rr) * DMOD + kt + scol], &Bs[(wv * 32 + i * 16) * 32]);
    }
    __syncthreads();
    bf16x8 af[4], bfr[4];
    #pragma unroll
    for (int mt = 0; mt < 4; ++mt)
      af[mt] = *(const bf16x8*)(&As[(wm * 64 + mt * 16 + lrow) * 32 + quad * 8]);
    #pragma unroll
    for (int nt = 0; nt < 4; ++nt)
      bfr[nt] = *(const bf16x8*)(&Bs[(wn * 64 + nt * 16 + lrow) * 32 + quad * 8]);
    #pragma unroll
    for (int mt = 0; mt < 4; ++mt)
      #pragma unroll
      for (int nt = 0; nt < 4; ++nt)
        acc[mt][nt] = __builtin_amdgcn_mfma_f32_16x16x32_bf16(af[mt], bfr[nt],
                                                              acc[mt][nt], 0, 0, 0);
    __syncthreads();
  }

  #pragma unroll
  for (int mt = 0; mt < 4; ++mt) {
    #pragma unroll
    for (int nt = 0; nt < 4; ++nt) {
      #pragma unroll
      for (int r = 0; r < 4; ++r) {
        int gm = tileM + wm * 64 + mt * 16 + quad * 4 + r;
        int gn = tileN + wn * 64 + nt * 16 + lrow;
        float v = acc[mt][nt][r];
        int which = gn >> 10, col = gn & 1023;
        int bb = gm >> 11, srw = gm & (SEQ - 1);
        int hh = col >> 6, dki = col & (DKH - 1);
        size_t idx = (((size_t)(bb * NH + hh)) * SEQ + srw) * DKH + dki;
        if (which == 0)      Qo[idx] = f2bf(v * 0.125f);
        else if (which == 1) Ko[idx] = f2bf(v);
        else                 Vo[idx] = f2bf(v);
      }
    }
  }
}

// ---------------- out GEMM: [4096 x 1024] * [1024 x 1024]^T -> fp32, 128x64 tiles ----------------
__global__ __launch_bounds__(256) void gemm_out(const u16* __restrict__ A,
                                                const u16* __restrict__ Bt,
                                                float* __restrict__ Co) {
  __shared__ __align__(16) u16 As[128 * 32];
  __shared__ __align__(16) u16 Bs[64 * 32];
  const int tid  = threadIdx.x;
  const int lane = tid & 63, wv = tid >> 6;
  const int wm   = wv & 1, wn = wv >> 1;
  const int lrow = lane & 15, quad = lane >> 4;
  const int tileM = blockIdx.x * 128, tileN = blockIdx.y * 64;
  const int srow = lane >> 2, scol = (lane & 3) * 8;

  const f32x4 fz = {0.f, 0.f, 0.f, 0.f};
  f32x4 acc[4][2];
  #pragma unroll
  for (int i = 0; i < 4; ++i) { acc[i][0] = fz; acc[i][1] = fz; }

  for (int kt = 0; kt < DMOD; kt += 32) {
    #pragma unroll
    for (int i = 0; i < 2; ++i)
      gll16(&A[(size_t)(tileM + wv * 32 + i * 16 + srow) * DMOD + kt + scol],
            &As[(wv * 32 + i * 16) * 32]);
    gll16(&Bt[(size_t)(tileN + wv * 16 + srow) * DMOD + kt + scol], &Bs[(wv * 16) * 32]);
    __syncthreads();
    bf16x8 af[4], bfr[2];
    #pragma unroll
    for (int mt = 0; mt < 4; ++mt)
      af[mt] = *(const bf16x8*)(&As[(wm * 64 + mt * 16 + lrow) * 32 + quad * 8]);
    #pragma unroll
    for (int nt = 0; nt < 2; ++nt)
      bfr[nt] = *(const bf16x8*)(&Bs[(wn * 32 + nt * 16 + lrow) * 32 + quad * 8]);
    #pragma unroll
    for (int mt = 0; mt < 4; ++mt)
      #pragma unroll
      for (int nt = 0; nt < 2; ++nt)
        acc[mt][nt] = __builtin_amdgcn_mfma_f32_16x16x32_bf16(af[mt], bfr[nt],
                                                              acc[mt][nt], 0, 0, 0);
    __syncthreads();
  }

  #pragma unroll
  for (int mt = 0; mt < 4; ++mt)
    #pragma unroll
    for (int nt = 0; nt < 2; ++nt)
      #pragma unroll
      for (int r = 0; r < 4; ++r) {
        int gm = tileM + wm * 64 + mt * 16 + quad * 4 + r;
        int gn = tileN + wn * 32 + nt * 16 + lrow;
        Co[(size_t)gm * DMOD + gn] = acc[mt][nt][r];
      }
}

// ---------------- causal flash attention, S^T formulation ----------------
// grid (32, BAT*NH); block 256 = 4 waves; one 64-row q-tile per block (fully resident
// grid: 1024 blocks x 40KB LDS = 4 blocks/CU). Wave w owns 16 q-columns.
// LDS unpadded, XOR-swizzled (chunk ^= row&7 / row&15) so gll16's contiguous dest
// constraint and conflict-free ds_reads coexist.
__global__ __launch_bounds__(256) void attn_k(const u16* __restrict__ Q,
                                              const u16* __restrict__ Kg,
                                              const u16* __restrict__ Vt,
                                              u16* __restrict__ Og) {
  __shared__ __align__(16) u16 Qs[64 * 64];    // [64 r][8 ch] swizzled, 8KB
  __shared__ __align__(16) u16 Ks[128 * 64];   // [128 r][8 ch] swizzled, 16KB
  __shared__ __align__(16) u16 Vs[64 * 128];   // [64 r][16 ch] swizzled, 16KB

  const int tid  = threadIdx.x;
  const int lane = tid & 63, w = tid >> 6;
  const int lrow = lane & 15, quad = lane >> 4;
  const int sw = lrow & 7;
  const int qt = blockIdx.x, bh = blockIdx.y;
  const int b = bh >> 4, h = bh & 15;

  const u16* Qbh = Q  + (size_t)bh * SEQ * DKH;
  const u16* Kbh = Kg + (size_t)bh * SEQ * DKH;
  const u16* Vbh = Vt + (size_t)bh * DKH * SEQ;

  // stage Q-tile: 512 chunks, swizzled
  #pragma unroll
  for (int k = 0; k < 2; ++k) {
    int ci = k * 256 + tid;
    int r = ci >> 3, c = ci & 7;
    gll16(&Qbh[(size_t)(qt * 64 + r) * DKH + ((c ^ (r & 7)) * 8)],
          &Qs[(k * 256 + w * 64) * 8]);
  }

  const int qglob = qt * 64 + w * 16 + lrow;
  const int qmaxw = qt * 64 + w * 16 + 15;
  const f32x4 fz = {0.f, 0.f, 0.f, 0.f};
  f32x4 oacc[4];
  #pragma unroll
  for (int d = 0; d < 4; ++d) oacc[d] = fz;
  float mrow = -1e30f, lsum = 0.f;

  const int jmax = qt >> 1;
  for (int j = 0; j <= jmax; ++j) {
    #pragma unroll
    for (int k = 0; k < 4; ++k) {
      int ci = k * 256 + tid;
      int r = ci >> 3, c = ci & 7;
      gll16(&Kbh[(size_t)(j * 128 + r) * DKH + ((c ^ (r & 7)) * 8)],
            &Ks[(k * 256 + w * 64) * 8]);
    }
    #pragma unroll
    for (int k = 0; k < 4; ++k) {
      int ci = k * 256 + tid;
      int r = ci >> 4, c = ci & 15;
      gll16(&Vbh[(size_t)r * SEQ + (size_t)(j * 16 + (c ^ (r & 15))) * 8],
            &Vs[(k * 256 + w * 64) * 8]);
    }
    __syncthreads();

    const int mlim = (j == jmax) ? (((qmaxw - j * 128) >> 4) + 1) : 8;

    f32x4 sacc[8];
    #pragma unroll
    for (int m = 0; m < 8; ++m) sacc[m] = fz;

    #pragma unroll
    for (int kk = 0; kk < 2; ++kk) {
      bf16x8 bq = *(const bf16x8*)(&Qs[((w * 16 + lrow) * 8 + ((kk * 4 + quad) ^ sw)) * 8]);
      #pragma unroll
      for (int m = 0; m < 8; ++m)
        if (m < mlim) {
          bf16x8 ak = *(const bf16x8*)(&Ks[((m * 16 + lrow) * 8 + ((kk * 4 + quad) ^ sw)) * 8]);
          sacc[m] = __builtin_amdgcn_mfma_f32_16x16x32_bf16(ak, bq, sacc[m], 0, 0, 0);
        }
    }

    if (j == jmax) {
      #pragma unroll
      for (int m = 0; m < 8; ++m)
        if (m < mlim)
          #pragma unroll
          for (int r = 0; r < 4; ++r) {
            int kg = j * 128 + m * 16 + quad * 4 + r;
            if (kg > qglob) sacc[m][r] = -1e30f;
          }
    }

    float mx = -1e30f;
    #pragma unroll
    for (int m = 0; m < 8; ++m)
      if (m < mlim)
        #pragma unroll
        for (int r = 0; r < 4; ++r) mx = fmaxf(mx, sacc[m][r]);
    mx = fmaxf(mx, __shfl_xor(mx, 16, 64));
    mx = fmaxf(mx, __shfl_xor(mx, 32, 64));
    float mnew = fmaxf(mrow, mx);
    float a = __expf(mrow - mnew);
    float s = 0.f;
    #pragma unroll
    for (int m = 0; m < 8; ++m)
      if (m < mlim)
        #pragma unroll
        for (int r = 0; r < 4; ++r) {
          float p = __expf(sacc[m][r] - mnew);
          sacc[m][r] = p;
          s += p;
        }
    s += __shfl_xor(s, 16, 64);
    s += __shfl_xor(s, 32, 64);
    lsum = lsum * a + s;
    mrow = mnew;
    #pragma unroll
    for (int d = 0; d < 4; ++d) oacc[d] *= a;

    // PV: O^T += V^T . P^T, P direct from registers (16x16x16 B-frag == C-layout)
    #pragma unroll
    for (int m = 0; m < 8; ++m)
      if (m < mlim) {
        union { u32 u[2]; s16x4 v; } pk;
        pk.u[0] = pack2bf(sacc[m][0], sacc[m][1]);
        pk.u[1] = pack2bf(sacc[m][2], sacc[m][3]);
        #pragma unroll
        for (int d = 0; d < 4; ++d) {
          s16x4 av = *(const s16x4*)(&Vs[(d * 16 + lrow) * 128 +
                                         ((2 * m + (quad >> 1)) ^ lrow) * 8 + (quad & 1) * 4]);
          oacc[d] = mfma16(av, pk.v, oacc[d]);
        }
      }
    __syncthreads();
  }

  float inv = 1.f / lsum;
  #pragma unroll
  for (int d = 0; d < 4; ++d)
    #pragma unroll
    for (int r = 0; r < 4; ++r) {
      int dg = d * 16 + quad * 4 + r;
      Og[((size_t)(b * SEQ + qglob)) * DMOD + h * DKH + dg] = f2bf(oacc[d][r] * inv);
    }
}

// ---------------- launch ----------------
extern "C" void kernel_launch(void* const* d_in, const int* in_sizes, int n_in,
                              void* d_out, int out_size, void* d_ws, size_t ws_size,
                              hipStream_t stream) {
  const float* x  = (const float*)d_in[0];
  const float* Wq = (const float*)d_in[1];
  const float* Wk = (const float*)d_in[2];
  const float* Wv = (const float*)d_in[3];
  const float* Wo = (const float*)d_in[4];

  u16* ws = (u16*)d_ws;
  const size_t WSZ = (size_t)DMOD * DMOD;
  const size_t TSZ = (size_t)BAT * NH * SEQ * DKH;
  u16* Wt  = ws;                 // 4 weights transposed, 4 x 1M elems
  u16* Wto = Wt + 3 * WSZ;
  u16* xb  = Wt + 4 * WSZ;       // x bf16; dead after QKV -> reused as Vtb
  u16* Qb  = xb + TSZ;
  u16* Kb  = Qb + TSZ;
  u16* Vo  = Kb + TSZ;           // V [b,h,s,dk]; dead after vtrans -> reused as Ob
  u16* Vtb = xb;
  u16* Ob  = Vo;

  transpose_all<<<dim3(32, 32, 4), dim3(32, 8), 0, stream>>>(Wq, Wk, Wv, Wo, Wt);
  convert_x<<<dim3(2048), 256, 0, stream>>>(x, xb);

  gemm_qkv<<<dim3(32, 24), 256, 0, stream>>>(xb, Wt, Qb, Kb, Vo);

  vtrans<<<dim3(SEQ / 32, DKH / 32, BAT * NH), dim3(32, 8), 0, stream>>>(Vo, Vtb);

  attn_k<<<dim3(32, BAT * NH), 256, 0, stream>>>(Qb, Kb, Vtb, Ob);

  gemm_out<<<dim3(32, 16), 256, 0, stream>>>(Ob, Wto, (float*)d_out);
}